// Round 2
// baseline (756.997 us; speedup 1.0000x reference)
//
#include <hip/hip_runtime.h>
#include <hip/hip_bf16.h>

#define BB 2
#define NN 16384
#define KK 16
#define CC 256
#define NHH 4
#define HDD 64
#define BN (BB*NN)   // 32768

typedef __attribute__((ext_vector_type(8))) short short8;
typedef __attribute__((ext_vector_type(4))) float f32x4;

__device__ __forceinline__ float bf2f(unsigned short u) {
    union { unsigned u32; float f; } x; x.u32 = ((unsigned)u) << 16; return x.f;
}
__device__ __forceinline__ unsigned short f2bf(float f) {
    union { float f; unsigned u; } x; x.f = f;
    unsigned r = x.u + 0x7FFFu + ((x.u >> 16) & 1u);
    return (unsigned short)(r >> 16);
}

// ---------------------------------------------------------------------------
// Prep: WqaT = (Wq @ blockdiag(Wa1))^T, WkaT, WpeaT likewise; plain transposes
// WvT, Wp2T, WoT; b_u = bp2 @ blockdiag(Wa1) + tile(ba1). All bf16 except b_u.
// grid (256, 7), 256 threads.
// ---------------------------------------------------------------------------
__global__ __launch_bounds__(256) void prep_kernel(
    const float* __restrict__ Wq, const float* __restrict__ Wk,
    const float* __restrict__ Wv, const float* __restrict__ Wp2,
    const float* __restrict__ Wo, const float* __restrict__ Wa1,
    const float* __restrict__ bp2, const float* __restrict__ ba1,
    unsigned short* WqaT, unsigned short* WkaT, unsigned short* WvT,
    unsigned short* WpeaT, unsigned short* Wp2T, unsigned short* WoT,
    float* b_u)
{
    const int z = blockIdx.y;
    const int t = threadIdx.x;
    if (z < 3) {
        const float* W = (z == 0) ? Wq : (z == 1) ? Wk : Wp2;
        unsigned short* out = (z == 0) ? WqaT : (z == 1) ? WkaT : WpeaT;
        const int k = blockIdx.x;                 // row of W
        __shared__ float wrow[CC];
        __shared__ float a1[HDD * HDD];
        wrow[t] = W[k * CC + t];
        for (int i = t; i < HDD * HDD; i += 256) a1[i] = Wa1[i];
        __syncthreads();
        const int c = t;
        const int h0 = c & ~63;
        const int cl = c & 63;
        float s = 0.f;
        #pragma unroll 8
        for (int j = 0; j < HDD; ++j) s += wrow[h0 + j] * a1[j * HDD + cl];
        out[c * CC + k] = f2bf(s);
    } else if (z < 6) {
        const float* W = (z == 3) ? Wv : (z == 4) ? Wp2 : Wo;
        unsigned short* out = (z == 3) ? WvT : (z == 4) ? Wp2T : WoT;
        const int k = blockIdx.x;
        out[t * CC + k] = f2bf(W[k * CC + t]);
    } else {
        if (blockIdx.x != 0) return;
        __shared__ float a1[HDD * HDD];
        for (int i = t; i < HDD * HDD; i += 256) a1[i] = Wa1[i];
        __syncthreads();
        const int c = t;
        const int h0 = c & ~63;
        const int cl = c & 63;
        float s = ba1[cl];
        #pragma unroll 8
        for (int j = 0; j < HDD; ++j) s += bp2[h0 + j] * a1[j * HDD + cl];
        b_u[c] = s;
    }
}

// h (f32) -> hbf (bf16). grid 8192 x 256, 4 elems/thread.
__global__ __launch_bounds__(256) void h2bf_kernel(const float* __restrict__ h,
                                                   unsigned short* __restrict__ hbf)
{
    const int i = blockIdx.x * blockDim.x + threadIdx.x;
    const float4 v = ((const float4*)h)[i];
    ushort4 o;
    o.x = f2bf(v.x); o.y = f2bf(v.y); o.z = f2bf(v.z); o.w = f2bf(v.w);
    ((ushort4*)hbf)[i] = o;
}

// ---------------------------------------------------------------------------
// 64-row MFMA GEMM: D[m0:m0+64, 0:256] = A[m0:m0+64, :] @ B (B given as BT[col][k]).
// FINAL=false: 3 weight/dest pairs via blockIdx.y, bf16 out.
// FINAL=true : single, f32 out + bias.
// block 256 = 4 waves; wave w owns columns [64w, 64w+64).
// ---------------------------------------------------------------------------
template<bool FINAL>
__global__ __launch_bounds__(256) void gemm64_kernel(
    const unsigned short* __restrict__ A,
    const unsigned short* __restrict__ BT0, const unsigned short* __restrict__ BT1,
    const unsigned short* __restrict__ BT2,
    unsigned short* D0, unsigned short* D1, unsigned short* D2,
    float* Dout, const float* __restrict__ bias)
{
    const int m0 = blockIdx.x * 64;
    const unsigned short* BT;
    unsigned short* Dst = nullptr;
    if (!FINAL) {
        const int z = blockIdx.y;
        BT  = (z == 0) ? BT0 : (z == 1) ? BT1 : BT2;
        Dst = (z == 0) ? D0  : (z == 1) ? D1  : D2;
    } else {
        BT = BT0;
    }

    __shared__ __align__(16) unsigned short As[64 * 264];
    const int t = threadIdx.x;
    #pragma unroll
    for (int i = 0; i < 8; ++i) {
        const int flat = i * 2048 + t * 8;
        const int r = flat >> 8, c = flat & 255;
        short8 v = *(const short8*)(A + (size_t)(m0 + r) * CC + c);
        *(short8*)(&As[r * 264 + c]) = v;
    }
    __syncthreads();

    const int lane = t & 63, w = t >> 6;
    const int lr = lane & 15, lg = lane >> 4;

    f32x4 acc[4][4];
    #pragma unroll
    for (int mi = 0; mi < 4; ++mi)
        #pragma unroll
        for (int ni = 0; ni < 4; ++ni) acc[mi][ni] = (f32x4){0.f, 0.f, 0.f, 0.f};

    #pragma unroll
    for (int kk = 0; kk < 8; ++kk) {
        const int ko = kk * 32 + lg * 8;
        short8 a[4];
        #pragma unroll
        for (int mi = 0; mi < 4; ++mi)
            a[mi] = *(const short8*)(&As[(mi * 16 + lr) * 264 + ko]);
        #pragma unroll
        for (int ni = 0; ni < 4; ++ni) {
            const int col = w * 64 + ni * 16 + lr;
            short8 b = *(const short8*)(BT + (size_t)col * CC + ko);
            #pragma unroll
            for (int mi = 0; mi < 4; ++mi)
                acc[mi][ni] = __builtin_amdgcn_mfma_f32_16x16x32_bf16(a[mi], b, acc[mi][ni], 0, 0, 0);
        }
    }

    #pragma unroll
    for (int mi = 0; mi < 4; ++mi) {
        #pragma unroll
        for (int ni = 0; ni < 4; ++ni) {
            const int col = w * 64 + ni * 16 + lr;
            #pragma unroll
            for (int reg = 0; reg < 4; ++reg) {
                const int row = m0 + mi * 16 + lg * 4 + reg;
                const float v = acc[mi][ni][reg];
                if (FINAL) Dout[(size_t)row * CC + col] = v + bias[col];
                else       Dst[(size_t)row * CC + col] = f2bf(v);
            }
        }
    }
}

// ---------------------------------------------------------------------------
// Fused per-point attention. Block = 4 points x 16 neighbors = 64 rows,
// 256 threads (4 waves; wave w = head w). Writes agg (bf16) to ws.
// ---------------------------------------------------------------------------
__global__ __launch_bounds__(256) void fused_attn_kernel(
    const float* __restrict__ P, const int* __restrict__ idx,
    const float* __restrict__ Wp1, const float* __restrict__ bp1,
    const float* __restrict__ Wa2, const float* __restrict__ bp2,
    const unsigned short* __restrict__ QAbf, const unsigned short* __restrict__ KAbf,
    const unsigned short* __restrict__ Vbf,  const unsigned short* __restrict__ WpeaT,
    const unsigned short* __restrict__ Wp2T, const float* __restrict__ b_u,
    unsigned short* __restrict__ aggbf)
{
    const int pt0 = blockIdx.x * 4;
    const int b = pt0 / NN;
    const int n0 = pt0 - b * NN;
    const int t = threadIdx.x;

    __shared__ int nbrL[64];
    __shared__ __align__(16) float geomL[64][4];
    __shared__ float QAs[4][CC];
    __shared__ float buL[CC];
    __shared__ float wa2L[HDD];
    __shared__ __align__(16) unsigned short hidL[64 * 264];
    __shared__ __align__(16) unsigned short KAs[64 * CC];
    __shared__ __align__(16) unsigned short Vs[64 * CC];
    __shared__ float logitsL[64][NHH];
    __shared__ float attnL[64][NHH];
    __shared__ __align__(16) unsigned short hbarL[16 * 264];
    __shared__ float vbarL[16][HDD];

    // ---- phase a: indices, geometry, per-point QA, constants ----
    if (t < 64) {
        const int g = t >> 4, k = t & 15;
        const int nb = idx[(size_t)(pt0 + g) * KK + k];
        nbrL[t] = nb;
        const float* Pb = P + (size_t)b * 3 * NN;
        const int nc = n0 + g;
        const float rx = Pb[nb] - Pb[nc];
        const float ry = Pb[NN + nb] - Pb[NN + nc];
        const float rz = Pb[2 * NN + nb] - Pb[2 * NN + nc];
        const float d = sqrtf(rx * rx + ry * ry + rz * rz);
        geomL[t][0] = rx; geomL[t][1] = ry; geomL[t][2] = rz; geomL[t][3] = d;
    }
    #pragma unroll
    for (int i = 0; i < 4; ++i) {
        const int e = t + i * 256;
        const int g = e >> 8, c = e & 255;
        QAs[g][c] = bf2f(QAbf[(size_t)(pt0 + g) * CC + c]);
    }
    buL[t] = b_u[t];
    if (t < 64) wa2L[t] = Wa2[t];
    __syncthreads();

    // ---- phase b: gather KA/V rows into LDS; compute hidden (relu MLP1) ----
    {
        const int r = t >> 2, seg = t & 3;
        const size_t src = ((size_t)b * NN + nbrL[r]) * CC;
        #pragma unroll
        for (int i = 0; i < 8; ++i) {
            const int c = seg * 64 + i * 8;
            *(short8*)(&KAs[r * CC + c]) = *(const short8*)(KAbf + src + c);
            *(short8*)(&Vs[r * CC + c])  = *(const short8*)(Vbf + src + c);
        }
    }
    {
        const int c = t;
        const float w0 = Wp1[c], w1 = Wp1[CC + c], w2 = Wp1[2 * CC + c], w3 = Wp1[3 * CC + c];
        const float bb = bp1[c];
        #pragma unroll 4
        for (int r = 0; r < 64; ++r) {
            const float4 gm = *(const float4*)(&geomL[r][0]);
            float v = fmaf(gm.x, w0, fmaf(gm.y, w1, fmaf(gm.z, w2, fmaf(gm.w, w3, bb))));
            hidL[r * 264 + c] = f2bf(fmaxf(v, 0.f));
        }
    }
    __syncthreads();

    const int lane = t & 63, w = t >> 6;
    const int lr = lane & 15, lg = lane >> 4;

    // ---- phase c: U = hidden @ Wpea (per-head 64 cols) via MFMA + logits ----
    f32x4 acc[4][4];
    #pragma unroll
    for (int mi = 0; mi < 4; ++mi)
        #pragma unroll
        for (int ni = 0; ni < 4; ++ni) acc[mi][ni] = (f32x4){0.f, 0.f, 0.f, 0.f};

    #pragma unroll
    for (int kk = 0; kk < 8; ++kk) {
        const int ko = kk * 32 + lg * 8;
        short8 a[4];
        #pragma unroll
        for (int mi = 0; mi < 4; ++mi)
            a[mi] = *(const short8*)(&hidL[(mi * 16 + lr) * 264 + ko]);
        #pragma unroll
        for (int ni = 0; ni < 4; ++ni) {
            const int col = w * 64 + ni * 16 + lr;
            short8 bfr = *(const short8*)(WpeaT + (size_t)col * CC + ko);
            #pragma unroll
            for (int mi = 0; mi < 4; ++mi)
                acc[mi][ni] = __builtin_amdgcn_mfma_f32_16x16x32_bf16(a[mi], bfr, acc[mi][ni], 0, 0, 0);
        }
    }

    #pragma unroll
    for (int mi = 0; mi < 4; ++mi) {
        #pragma unroll
        for (int reg = 0; reg < 4; ++reg) {
            const int r = mi * 16 + lg * 4 + reg;
            float pl = 0.f;
            #pragma unroll
            for (int ni = 0; ni < 4; ++ni) {
                const int cl = ni * 16 + lr;
                const int c = w * 64 + cl;
                const float u = QAs[mi][c] - bf2f(KAs[r * CC + c]) + acc[mi][ni][reg] + buL[c];
                pl += fmaxf(u, 0.f) * wa2L[cl];
            }
            pl += __shfl_xor(pl, 1, 64);
            pl += __shfl_xor(pl, 2, 64);
            pl += __shfl_xor(pl, 4, 64);
            pl += __shfl_xor(pl, 8, 64);
            if (lr == 0) logitsL[r][w] = pl;
        }
    }
    __syncthreads();

    // ---- phase d: softmax over K=16 per (point, head) ----
    if (t < 16) {
        const int g = t >> 2, hh = t & 3;
        float m = -1e30f;
        #pragma unroll
        for (int k = 0; k < 16; ++k) m = fmaxf(m, logitsL[g * 16 + k][hh]);
        float s = 0.f;
        float e[16];
        #pragma unroll
        for (int k = 0; k < 16; ++k) {
            e[k] = __expf(logitsL[g * 16 + k][hh] - m);
            s += e[k];
        }
        const float inv = 1.f / s;
        #pragma unroll
        for (int k = 0; k < 16; ++k) attnL[g * 16 + k][hh] = e[k] * inv;
    }
    __syncthreads();

    // ---- phase e: hbar = sum_k attn*hidden (per head), vbar = sum_k attn*V ----
    {
        const int c = t;
        #pragma unroll
        for (int g = 0; g < 4; ++g) {
            float hv[16];
            #pragma unroll
            for (int k = 0; k < 16; ++k) hv[k] = bf2f(hidL[(g * 16 + k) * 264 + c]);
            #pragma unroll
            for (int hh = 0; hh < NHH; ++hh) {
                float s = 0.f;
                #pragma unroll
                for (int k = 0; k < 16; ++k) s += attnL[g * 16 + k][hh] * hv[k];
                hbarL[(g * 4 + hh) * 264 + c] = f2bf(s);
            }
        }
    }
    {
        const int d = t & 63;
        const int i0 = t >> 6;
        #pragma unroll
        for (int i = 0; i < 4; ++i) {
            const int gh = i0 * 4 + i;
            const int g = gh >> 2, hh = gh & 3;
            float s = 0.f;
            #pragma unroll
            for (int k = 0; k < 16; ++k)
                s += attnL[g * 16 + k][hh] * bf2f(Vs[(g * 16 + k) * CC + hh * 64 + d]);
            vbarL[gh][d] = s;
        }
    }
    __syncthreads();

    // ---- phase f: pe_agg = hbar @ Wp2 (head cols) via MFMA; agg = vbar+pe+bp2 ----
    f32x4 acc2[4];
    #pragma unroll
    for (int ni = 0; ni < 4; ++ni) acc2[ni] = (f32x4){0.f, 0.f, 0.f, 0.f};
    #pragma unroll
    for (int kk = 0; kk < 8; ++kk) {
        const int ko = kk * 32 + lg * 8;
        short8 a = *(const short8*)(&hbarL[lr * 264 + ko]);
        #pragma unroll
        for (int ni = 0; ni < 4; ++ni) {
            const int col = w * 64 + ni * 16 + lr;
            short8 bfr = *(const short8*)(Wp2T + (size_t)col * CC + ko);
            acc2[ni] = __builtin_amdgcn_mfma_f32_16x16x32_bf16(a, bfr, acc2[ni], 0, 0, 0);
        }
    }
    #pragma unroll
    for (int ni = 0; ni < 4; ++ni) {
        const int cl = ni * 16 + lr;
        const int c = w * 64 + cl;
        // output row = lg*4 + reg; we need rows with (row & 3) == w, i.e. reg == w.
        float pv;
        if      (w == 0) pv = acc2[ni][0];
        else if (w == 1) pv = acc2[ni][1];
        else if (w == 2) pv = acc2[ni][2];
        else             pv = acc2[ni][3];
        const float v = pv + vbarL[lg * 4 + w][cl] + bp2[c];
        aggbf[(size_t)(pt0 + lg) * CC + c] = f2bf(v);
    }
}

// ---------------------------------------------------------------------------
extern "C" void kernel_launch(void* const* d_in, const int* in_sizes, int n_in,
                              void* d_out, int out_size, void* d_ws, size_t ws_size,
                              hipStream_t stream)
{
    const float* h   = (const float*)d_in[0];
    const float* P   = (const float*)d_in[1];
    const int*   idx = (const int*)d_in[2];
    const float* Wq  = (const float*)d_in[3];
    const float* Wk  = (const float*)d_in[4];
    const float* Wv  = (const float*)d_in[5];
    const float* Wp1 = (const float*)d_in[6];
    const float* bp1 = (const float*)d_in[7];
    const float* Wp2 = (const float*)d_in[8];
    const float* bp2 = (const float*)d_in[9];
    const float* Wa1 = (const float*)d_in[10];
    const float* ba1 = (const float*)d_in[11];
    const float* Wa2 = (const float*)d_in[12];
    const float* Wo  = (const float*)d_in[14];
    const float* bo  = (const float*)d_in[15];

    char* ws = (char*)d_ws;
    const size_t MB16 = 16777216;   // BN*CC*2 bytes
    unsigned short* WqaT  = (unsigned short*)(ws + 0);
    unsigned short* WkaT  = (unsigned short*)(ws + 131072);
    unsigned short* WvT   = (unsigned short*)(ws + 262144);
    unsigned short* WpeaT = (unsigned short*)(ws + 393216);
    unsigned short* Wp2T  = (unsigned short*)(ws + 524288);
    unsigned short* WoT   = (unsigned short*)(ws + 655360);
    float*          b_u   = (float*)(ws + 786432);
    const size_t base = 1 << 20;
    unsigned short* hbf   = (unsigned short*)(ws + base + 0 * MB16);
    unsigned short* QAbf  = (unsigned short*)(ws + base + 1 * MB16);
    unsigned short* KAbf  = (unsigned short*)(ws + base + 2 * MB16);
    unsigned short* Vbf   = (unsigned short*)(ws + base + 3 * MB16);
    unsigned short* aggbf = (unsigned short*)(ws + base + 4 * MB16);
    if (ws_size < base + 5 * MB16) return;   // insufficient scratch -> fail loudly

    prep_kernel<<<dim3(256, 7), 256, 0, stream>>>(Wq, Wk, Wv, Wp2, Wo, Wa1, bp2, ba1,
                                                  WqaT, WkaT, WvT, WpeaT, Wp2T, WoT, b_u);
    h2bf_kernel<<<BN * CC / 4 / 256, 256, 0, stream>>>(h, hbf);
    gemm64_kernel<false><<<dim3(BN / 64, 3), 256, 0, stream>>>(
        hbf, WqaT, WkaT, WvT, QAbf, KAbf, Vbf, nullptr, nullptr);
    fused_attn_kernel<<<BN / 4, 256, 0, stream>>>(P, idx, Wp1, bp1, Wa2, bp2,
                                                  QAbf, KAbf, Vbf, WpeaT, Wp2T, b_u, aggbf);
    gemm64_kernel<true><<<dim3(BN / 64, 1), 256, 0, stream>>>(
        aggbf, WoT, nullptr, nullptr, nullptr, nullptr, nullptr, (float*)d_out, bo);
}

// Round 3
// 413.803 us; speedup vs baseline: 1.8294x; 1.8294x over previous
//
#include <hip/hip_runtime.h>
#include <hip/hip_bf16.h>

#define BB 2
#define NN 16384
#define KK 16
#define CC 256
#define NHH 4
#define HDD 64
#define BN (BB*NN)   // 32768

typedef __attribute__((ext_vector_type(8))) short short8;
typedef __attribute__((ext_vector_type(4))) float f32x4;

__device__ __forceinline__ float bf2f(unsigned short u) {
    union { unsigned u32; float f; } x; x.u32 = ((unsigned)u) << 16; return x.f;
}
__device__ __forceinline__ unsigned short f2bf(float f) {
    union { float f; unsigned u; } x; x.f = f;
    unsigned r = x.u + 0x7FFFu + ((x.u >> 16) & 1u);
    return (unsigned short)(r >> 16);
}

// ---------------------------------------------------------------------------
// Prep: WqaT = (Wq @ blockdiag(Wa1))^T, WkaT, WpeaT likewise; plain transposes
// WvT, Wp2T, WoT; b_u = bp2 @ blockdiag(Wa1) + tile(ba1). All bf16 except b_u.
// grid (256, 7), 256 threads.
// ---------------------------------------------------------------------------
__global__ __launch_bounds__(256) void prep_kernel(
    const float* __restrict__ Wq, const float* __restrict__ Wk,
    const float* __restrict__ Wv, const float* __restrict__ Wp2,
    const float* __restrict__ Wo, const float* __restrict__ Wa1,
    const float* __restrict__ bp2, const float* __restrict__ ba1,
    unsigned short* WqaT, unsigned short* WkaT, unsigned short* WvT,
    unsigned short* WpeaT, unsigned short* Wp2T, unsigned short* WoT,
    float* b_u)
{
    const int z = blockIdx.y;
    const int t = threadIdx.x;
    if (z < 3) {
        const float* W = (z == 0) ? Wq : (z == 1) ? Wk : Wp2;
        unsigned short* out = (z == 0) ? WqaT : (z == 1) ? WkaT : WpeaT;
        const int k = blockIdx.x;                 // row of W
        __shared__ float wrow[CC];
        __shared__ float a1[HDD * HDD];
        wrow[t] = W[k * CC + t];
        for (int i = t; i < HDD * HDD; i += 256) a1[i] = Wa1[i];
        __syncthreads();
        const int c = t;
        const int h0 = c & ~63;
        const int cl = c & 63;
        float s = 0.f;
        #pragma unroll 8
        for (int j = 0; j < HDD; ++j) s += wrow[h0 + j] * a1[j * HDD + cl];
        out[c * CC + k] = f2bf(s);
    } else if (z < 6) {
        const float* W = (z == 3) ? Wv : (z == 4) ? Wp2 : Wo;
        unsigned short* out = (z == 3) ? WvT : (z == 4) ? Wp2T : WoT;
        const int k = blockIdx.x;
        out[t * CC + k] = f2bf(W[k * CC + t]);
    } else {
        if (blockIdx.x != 0) return;
        __shared__ float a1[HDD * HDD];
        for (int i = t; i < HDD * HDD; i += 256) a1[i] = Wa1[i];
        __syncthreads();
        const int c = t;
        const int h0 = c & ~63;
        const int cl = c & 63;
        float s = ba1[cl];
        #pragma unroll 8
        for (int j = 0; j < HDD; ++j) s += bp2[h0 + j] * a1[j * HDD + cl];
        b_u[c] = s;
    }
}

// h (f32) -> hbf (bf16). grid 8192 x 256, 4 elems/thread.
__global__ __launch_bounds__(256) void h2bf_kernel(const float* __restrict__ h,
                                                   unsigned short* __restrict__ hbf)
{
    const int i = blockIdx.x * blockDim.x + threadIdx.x;
    const float4 v = ((const float4*)h)[i];
    ushort4 o;
    o.x = f2bf(v.x); o.y = f2bf(v.y); o.z = f2bf(v.z); o.w = f2bf(v.w);
    ((ushort4*)hbf)[i] = o;
}

// ---------------------------------------------------------------------------
// 64-row MFMA GEMM: D[m0:m0+64, 0:256] = A[m0:m0+64, :] @ B (B given as BT[col][k]).
// FINAL=false: 3 weight/dest pairs via blockIdx.y, bf16 out.
// FINAL=true : single, f32 out + bias.
// block 256 = 4 waves; wave w owns columns [64w, 64w+64).
// ---------------------------------------------------------------------------
template<bool FINAL>
__global__ __launch_bounds__(256) void gemm64_kernel(
    const unsigned short* __restrict__ A,
    const unsigned short* __restrict__ BT0, const unsigned short* __restrict__ BT1,
    const unsigned short* __restrict__ BT2,
    unsigned short* D0, unsigned short* D1, unsigned short* D2,
    float* Dout, const float* __restrict__ bias)
{
    const int m0 = blockIdx.x * 64;
    const unsigned short* BT;
    unsigned short* Dst = nullptr;
    if (!FINAL) {
        const int z = blockIdx.y;
        BT  = (z == 0) ? BT0 : (z == 1) ? BT1 : BT2;
        Dst = (z == 0) ? D0  : (z == 1) ? D1  : D2;
    } else {
        BT = BT0;
    }

    __shared__ __align__(16) unsigned short As[64 * 264];
    const int t = threadIdx.x;
    #pragma unroll
    for (int i = 0; i < 8; ++i) {
        const int flat = i * 2048 + t * 8;
        const int r = flat >> 8, c = flat & 255;
        short8 v = *(const short8*)(A + (size_t)(m0 + r) * CC + c);
        *(short8*)(&As[r * 264 + c]) = v;
    }
    __syncthreads();

    const int lane = t & 63, w = t >> 6;
    const int lr = lane & 15, lg = lane >> 4;

    f32x4 acc[4][4];
    #pragma unroll
    for (int mi = 0; mi < 4; ++mi)
        #pragma unroll
        for (int ni = 0; ni < 4; ++ni) acc[mi][ni] = (f32x4){0.f, 0.f, 0.f, 0.f};

    #pragma unroll
    for (int kk = 0; kk < 8; ++kk) {
        const int ko = kk * 32 + lg * 8;
        short8 a[4];
        #pragma unroll
        for (int mi = 0; mi < 4; ++mi)
            a[mi] = *(const short8*)(&As[(mi * 16 + lr) * 264 + ko]);
        #pragma unroll
        for (int ni = 0; ni < 4; ++ni) {
            const int col = w * 64 + ni * 16 + lr;
            short8 b = *(const short8*)(BT + (size_t)col * CC + ko);
            #pragma unroll
            for (int mi = 0; mi < 4; ++mi)
                acc[mi][ni] = __builtin_amdgcn_mfma_f32_16x16x32_bf16(a[mi], b, acc[mi][ni], 0, 0, 0);
        }
    }

    #pragma unroll
    for (int mi = 0; mi < 4; ++mi) {
        #pragma unroll
        for (int ni = 0; ni < 4; ++ni) {
            const int col = w * 64 + ni * 16 + lr;
            #pragma unroll
            for (int reg = 0; reg < 4; ++reg) {
                const int row = m0 + mi * 16 + lg * 4 + reg;
                const float v = acc[mi][ni][reg];
                if (FINAL) Dout[(size_t)row * CC + col] = v + bias[col];
                else       Dst[(size_t)row * CC + col] = f2bf(v);
            }
        }
    }
}

// ---------------------------------------------------------------------------
// Fused per-point attention. Block = 4 points x 16 neighbors = 64 rows,
// 256 threads (4 waves; wave w = head w).
// LDS diet: no KA/V staging (direct global reads; neighbor rows are random so
// staging buys no reuse) -> 51200 B -> 3 blocks/CU (12 waves/CU vs 4 before).
// ---------------------------------------------------------------------------
__global__ __launch_bounds__(256, 3) void fused_attn_kernel(
    const float* __restrict__ P, const int* __restrict__ idx,
    const float* __restrict__ Wp1, const float* __restrict__ bp1,
    const float* __restrict__ Wa2, const float* __restrict__ bp2,
    const unsigned short* __restrict__ QAbf, const unsigned short* __restrict__ KAbf,
    const unsigned short* __restrict__ Vbf,  const unsigned short* __restrict__ WpeaT,
    const unsigned short* __restrict__ Wp2T, const float* __restrict__ b_u,
    unsigned short* __restrict__ aggbf)
{
    const int pt0 = blockIdx.x * 4;
    const int b = pt0 >> 14;          // pt0 / NN
    const int n0 = pt0 & (NN - 1);
    const int t = threadIdx.x;

    __shared__ int nbrL[64];                                   //   256 B
    __shared__ __align__(16) float geomL[64][4];               //  1024 B
    __shared__ __align__(16) unsigned short QAsb[4 * CC];      //  2048 B
    __shared__ float buL[CC];                                  //  1024 B
    __shared__ float wa2L[HDD];                                //   256 B
    __shared__ __align__(16) unsigned short hidL[64 * 264];    // 33792 B
    __shared__ float logitsL[64][NHH];                         //  1024 B
    __shared__ float attnL[64][NHH];                           //  1024 B
    __shared__ __align__(16) unsigned short hbarL[16 * 264];   //  8448 B
    __shared__ unsigned short vbarL[16 * 72];                  //  2304 B
    // total 51200 B -> 3 blocks/CU

    // ---- phase a: indices, geometry, QA copy, constants ----
    if (t < 64) {
        const int g = t >> 4, k = t & 15;
        const int nb = idx[(size_t)(pt0 + g) * KK + k];
        nbrL[t] = nb;
        const float* Pb = P + (size_t)b * 3 * NN;
        const int nc = n0 + g;
        const float rx = Pb[nb] - Pb[nc];
        const float ry = Pb[NN + nb] - Pb[NN + nc];
        const float rz = Pb[2 * NN + nb] - Pb[2 * NN + nc];
        const float d = sqrtf(rx * rx + ry * ry + rz * rz);
        geomL[t][0] = rx; geomL[t][1] = ry; geomL[t][2] = rz; geomL[t][3] = d;
    }
    {
        const int e = t * 4;  // 1024 ushorts over 256 threads
        *(ushort4*)(&QAsb[e]) = *(const ushort4*)(QAbf + (size_t)pt0 * CC + e);
    }
    buL[t] = b_u[t];
    if (t < 64) wa2L[t] = Wa2[t];
    __syncthreads();

    // ---- phase b: hidden = relu(geom @ Wp1 + bp1), bf16 in LDS ----
    {
        const int c = t;
        const float w0 = Wp1[c], w1 = Wp1[CC + c], w2 = Wp1[2 * CC + c], w3 = Wp1[3 * CC + c];
        const float bb = bp1[c];
        #pragma unroll 4
        for (int r = 0; r < 64; ++r) {
            const float4 gm = *(const float4*)(&geomL[r][0]);
            float v = fmaf(gm.x, w0, fmaf(gm.y, w1, fmaf(gm.z, w2, fmaf(gm.w, w3, bb))));
            hidL[r * 264 + c] = f2bf(fmaxf(v, 0.f));
        }
    }
    __syncthreads();

    const int lane = t & 63, w = t >> 6;
    const int lr = lane & 15, lg = lane >> 4;

    // ---- phase c: U = hidden @ Wpea (per-head 64 cols) via MFMA + logits ----
    f32x4 acc[4][4];
    #pragma unroll
    for (int mi = 0; mi < 4; ++mi)
        #pragma unroll
        for (int ni = 0; ni < 4; ++ni) acc[mi][ni] = (f32x4){0.f, 0.f, 0.f, 0.f};

    #pragma unroll
    for (int kk = 0; kk < 8; ++kk) {
        const int ko = kk * 32 + lg * 8;
        short8 a[4];
        #pragma unroll
        for (int mi = 0; mi < 4; ++mi)
            a[mi] = *(const short8*)(&hidL[(mi * 16 + lr) * 264 + ko]);
        #pragma unroll
        for (int ni = 0; ni < 4; ++ni) {
            const int col = w * 64 + ni * 16 + lr;
            short8 bfr = *(const short8*)(WpeaT + (size_t)col * CC + ko);
            #pragma unroll
            for (int mi = 0; mi < 4; ++mi)
                acc[mi][ni] = __builtin_amdgcn_mfma_f32_16x16x32_bf16(a[mi], bfr, acc[mi][ni], 0, 0, 0);
        }
    }

    // logits epilogue: KA read directly from global (random rows; 128 B head
    // slice per row is one cacheline -- same traffic as staging, no LDS).
    #pragma unroll
    for (int mi = 0; mi < 4; ++mi) {
        unsigned short ka[4][4];
        #pragma unroll
        for (int reg = 0; reg < 4; ++reg) {
            const int r = mi * 16 + lg * 4 + reg;
            const size_t base = ((size_t)b * NN + nbrL[r]) * CC;
            #pragma unroll
            for (int ni = 0; ni < 4; ++ni)
                ka[reg][ni] = KAbf[base + w * 64 + ni * 16 + lr];
        }
        #pragma unroll
        for (int reg = 0; reg < 4; ++reg) {
            float pl = 0.f;
            #pragma unroll
            for (int ni = 0; ni < 4; ++ni) {
                const int c = w * 64 + ni * 16 + lr;
                const float u = bf2f(QAsb[mi * CC + c]) - bf2f(ka[reg][ni])
                              + acc[mi][ni][reg] + buL[c];
                pl += fmaxf(u, 0.f) * wa2L[ni * 16 + lr];
            }
            pl += __shfl_xor(pl, 1);
            pl += __shfl_xor(pl, 2);
            pl += __shfl_xor(pl, 4);
            pl += __shfl_xor(pl, 8);
            if (lr == 0) logitsL[mi * 16 + lg * 4 + reg][w] = pl;
        }
    }
    __syncthreads();

    // ---- phase d: softmax over K=16, one (point,head) pair per 16 lanes ----
    {
        const int p = t >> 4, k = t & 15;
        const int g = p >> 2, hh = p & 3;
        const float v = logitsL[g * 16 + k][hh];
        float m = v;
        m = fmaxf(m, __shfl_xor(m, 1));
        m = fmaxf(m, __shfl_xor(m, 2));
        m = fmaxf(m, __shfl_xor(m, 4));
        m = fmaxf(m, __shfl_xor(m, 8));
        const float e = __expf(v - m);
        float s = e;
        s += __shfl_xor(s, 1);
        s += __shfl_xor(s, 2);
        s += __shfl_xor(s, 4);
        s += __shfl_xor(s, 8);
        attnL[g * 16 + k][hh] = e / s;
    }
    __syncthreads();

    // ---- phase e: hbar = sum_k attn*hidden (per head); vbar from global V ----
    {
        const int c = t;
        #pragma unroll
        for (int g = 0; g < 4; ++g) {
            float hv[16];
            #pragma unroll
            for (int k = 0; k < 16; ++k) hv[k] = bf2f(hidL[(g * 16 + k) * 264 + c]);
            #pragma unroll
            for (int hh = 0; hh < NHH; ++hh) {
                float s = 0.f;
                #pragma unroll
                for (int k = 0; k < 16; ++k) s += attnL[g * 16 + k][hh] * hv[k];
                hbarL[(g * 4 + hh) * 264 + c] = f2bf(s);
            }
        }
    }
    {
        const int d = lane;
        #pragma unroll
        for (int i = 0; i < 4; ++i) {
            const int gh = w * 4 + i;
            const int g = gh >> 2, hh = gh & 3;
            float s = 0.f;
            #pragma unroll
            for (int k = 0; k < 16; ++k) {
                const int r = g * 16 + k;
                const size_t src = ((size_t)b * NN + nbrL[r]) * CC + hh * 64 + d;
                s += attnL[r][hh] * bf2f(Vbf[src]);
            }
            vbarL[gh * 72 + d] = f2bf(s);
        }
    }
    __syncthreads();

    // ---- phase f: pe_agg = hbar @ Wp2 (head cols) via MFMA; agg out ----
    f32x4 acc2[4];
    #pragma unroll
    for (int ni = 0; ni < 4; ++ni) acc2[ni] = (f32x4){0.f, 0.f, 0.f, 0.f};
    #pragma unroll
    for (int kk = 0; kk < 8; ++kk) {
        const int ko = kk * 32 + lg * 8;
        short8 a = *(const short8*)(&hbarL[lr * 264 + ko]);
        #pragma unroll
        for (int ni = 0; ni < 4; ++ni) {
            const int col = w * 64 + ni * 16 + lr;
            short8 bfr = *(const short8*)(Wp2T + (size_t)col * CC + ko);
            acc2[ni] = __builtin_amdgcn_mfma_f32_16x16x32_bf16(a, bfr, acc2[ni], 0, 0, 0);
        }
    }
    #pragma unroll
    for (int ni = 0; ni < 4; ++ni) {
        const int cl = ni * 16 + lr;
        const int c = w * 64 + cl;
        // output row = lg*4 + reg; rows with hh == w  <=>  reg == w.
        float pv;
        if      (w == 0) pv = acc2[ni][0];
        else if (w == 1) pv = acc2[ni][1];
        else if (w == 2) pv = acc2[ni][2];
        else             pv = acc2[ni][3];
        const float v = pv + bf2f(vbarL[(lg * 4 + w) * 72 + cl]) + bp2[c];
        aggbf[(size_t)(pt0 + lg) * CC + c] = f2bf(v);
    }
}

// ---------------------------------------------------------------------------
extern "C" void kernel_launch(void* const* d_in, const int* in_sizes, int n_in,
                              void* d_out, int out_size, void* d_ws, size_t ws_size,
                              hipStream_t stream)
{
    const float* h   = (const float*)d_in[0];
    const float* P   = (const float*)d_in[1];
    const int*   idx = (const int*)d_in[2];
    const float* Wq  = (const float*)d_in[3];
    const float* Wk  = (const float*)d_in[4];
    const float* Wv  = (const float*)d_in[5];
    const float* Wp1 = (const float*)d_in[6];
    const float* bp1 = (const float*)d_in[7];
    const float* Wp2 = (const float*)d_in[8];
    const float* bp2 = (const float*)d_in[9];
    const float* Wa1 = (const float*)d_in[10];
    const float* ba1 = (const float*)d_in[11];
    const float* Wa2 = (const float*)d_in[12];
    const float* Wo  = (const float*)d_in[14];
    const float* bo  = (const float*)d_in[15];

    char* ws = (char*)d_ws;
    const size_t MB16 = 16777216;   // BN*CC*2 bytes
    unsigned short* WqaT  = (unsigned short*)(ws + 0);
    unsigned short* WkaT  = (unsigned short*)(ws + 131072);
    unsigned short* WvT   = (unsigned short*)(ws + 262144);
    unsigned short* WpeaT = (unsigned short*)(ws + 393216);
    unsigned short* Wp2T  = (unsigned short*)(ws + 524288);
    unsigned short* WoT   = (unsigned short*)(ws + 655360);
    float*          b_u   = (float*)(ws + 786432);
    const size_t base = 1 << 20;
    unsigned short* hbf   = (unsigned short*)(ws + base + 0 * MB16);
    unsigned short* QAbf  = (unsigned short*)(ws + base + 1 * MB16);
    unsigned short* KAbf  = (unsigned short*)(ws + base + 2 * MB16);
    unsigned short* Vbf   = (unsigned short*)(ws + base + 3 * MB16);
    unsigned short* aggbf = (unsigned short*)(ws + base + 4 * MB16);
    if (ws_size < base + 5 * MB16) return;   // insufficient scratch -> fail loudly

    prep_kernel<<<dim3(256, 7), 256, 0, stream>>>(Wq, Wk, Wv, Wp2, Wo, Wa1, bp2, ba1,
                                                  WqaT, WkaT, WvT, WpeaT, Wp2T, WoT, b_u);
    h2bf_kernel<<<BN * CC / 4 / 256, 256, 0, stream>>>(h, hbf);
    gemm64_kernel<false><<<dim3(BN / 64, 3), 256, 0, stream>>>(
        hbf, WqaT, WkaT, WvT, QAbf, KAbf, Vbf, nullptr, nullptr);
    fused_attn_kernel<<<BN / 4, 256, 0, stream>>>(P, idx, Wp1, bp1, Wa2, bp2,
                                                  QAbf, KAbf, Vbf, WpeaT, Wp2T, b_u, aggbf);
    gemm64_kernel<true><<<dim3(BN / 64, 1), 256, 0, stream>>>(
        aggbf, WoT, nullptr, nullptr, nullptr, nullptr, nullptr, (float*)d_out, bo);
}